// Round 6
// baseline (2660.177 us; speedup 1.0000x reference)
//
#include <hip/hip_runtime.h>
#include <hip/hip_bf16.h>

// PhiNet: per-point MLP 16->128->128->64 (ReLU each) + segment mean (4096 segs x 256 pts).
// One block per segment, one lane per point. Weights via wave-uniform s_load (SGPR path),
// activations fully register-resident with static indexing (rule #20). W3 pre-transposed
// into d_ws so the fused L2/L3 loop reads contiguous scalar cachelines for both W2 and W3.

#define THREADS 256

// ---- one-shot prep: W3 [64][128] -> W3t [128][64] ----
__global__ void transpose_w3(const float* __restrict__ W3, float* __restrict__ W3t) {
    int idx = blockIdx.x * blockDim.x + threadIdx.x;   // 0 .. 8191
    int k = idx >> 7;          // 0..63   (row of W3)
    int o = idx & 127;         // 0..127  (col of W3)
    if (idx < 64 * 128) W3t[o * 64 + k] = W3[k * 128 + o];
}

__global__ __launch_bounds__(THREADS, 2)
void phinet_kernel(const float* __restrict__ x,
                   const float* __restrict__ W1, const float* __restrict__ b1,
                   const float* __restrict__ W2, const float* __restrict__ b2,
                   const float* __restrict__ W3t, const float* __restrict__ b3,
                   const int*   __restrict__ seg,
                   float* __restrict__ out, int N)
{
    const int s     = blockIdx.x;
    const int tid   = threadIdx.x;
    const int lane  = tid & 63;
    const int wave  = tid >> 6;
    const int start = seg[s];
    const int end   = seg[s + 1];

    __shared__ float partial[4][64];
    partial[wave][lane] = 0.0f;
    __syncthreads();

    for (int p = start + tid; p < end; p += THREADS) {
        // ---- load point features (coalesced: lane-consecutive p) ----
        float xv[16];
#pragma unroll
        for (int c = 0; c < 16; ++c)
            xv[c] = x[(size_t)c * (size_t)N + (size_t)p];

        // ---- layer 1: 16 -> 128, ReLU (W1 wave-uniform -> s_load) ----
        float h1[128];
#pragma unroll
        for (int j = 0; j < 128; ++j) {
            float a = b1[j];
#pragma unroll
            for (int c = 0; c < 16; ++c)
                a = fmaf(W1[j * 16 + c], xv[c], a);
            h1[j] = fmaxf(a, 0.0f);
        }

        // ---- layer 3 accumulators (init with bias) ----
        float h3[64];
#pragma unroll
        for (int k = 0; k < 64; ++k) h3[k] = b3[k];

        // ---- layer 2 (128x128) fused with layer 3 (64x128) ----
        // W2 row: 128 contiguous floats; W3t row: 64 contiguous floats -> s_load_dwordx16
        // runs. unroll 4: wider window of independent s_load chains for latency hiding.
#pragma unroll 4
        for (int o = 0; o < 128; ++o) {
            float a0 = 0.0f, a1 = 0.0f, a2 = 0.0f, a3 = 0.0f;
#pragma unroll
            for (int i = 0; i < 128; i += 4) {
                a0 = fmaf(W2[o * 128 + i + 0], h1[i + 0], a0);
                a1 = fmaf(W2[o * 128 + i + 1], h1[i + 1], a1);
                a2 = fmaf(W2[o * 128 + i + 2], h1[i + 2], a2);
                a3 = fmaf(W2[o * 128 + i + 3], h1[i + 3], a3);
            }
            const float h2 = fmaxf(b2[o] + ((a0 + a1) + (a2 + a3)), 0.0f);
#pragma unroll
            for (int k = 0; k < 64; ++k)
                h3[k] = fmaf(W3t[o * 64 + k], h2, h3[k]);
        }

        // ---- per-wave butterfly reduce each of the 64 features ----
#pragma unroll
        for (int k = 0; k < 64; ++k) {
            float v = fmaxf(h3[k], 0.0f);
            v += __shfl_xor(v, 1);
            v += __shfl_xor(v, 2);
            v += __shfl_xor(v, 4);
            v += __shfl_xor(v, 8);
            v += __shfl_xor(v, 16);
            v += __shfl_xor(v, 32);
            if (lane == 0) partial[wave][k] += v;
        }
    }

    __syncthreads();

    // ---- final cross-wave reduce + mean, one thread per feature ----
    if (tid < 64) {
        const float cnt = (float)(end - start);
        float v = partial[0][tid] + partial[1][tid] + partial[2][tid] + partial[3][tid];
        out[(size_t)s * 64 + tid] = v / cnt;
    }
}

extern "C" void kernel_launch(void* const* d_in, const int* in_sizes, int n_in,
                              void* d_out, int out_size, void* d_ws, size_t ws_size,
                              hipStream_t stream) {
    const float* x  = (const float*)d_in[0];
    const float* W1 = (const float*)d_in[1];
    const float* b1 = (const float*)d_in[2];
    const float* W2 = (const float*)d_in[3];
    const float* b2 = (const float*)d_in[4];
    const float* W3 = (const float*)d_in[5];
    const float* b3 = (const float*)d_in[6];
    const int*  seg = (const int*)d_in[7];
    float* out = (float*)d_out;

    const int N = in_sizes[0] / 16;          // x is [1, 16, N]
    const int S = in_sizes[7] - 1;           // sample_indices has S+1 entries

    float* W3t = (float*)d_ws;               // 128*64*4 = 32 KB scratch

    transpose_w3<<<(64 * 128 + 255) / 256, 256, 0, stream>>>(W3, W3t);
    phinet_kernel<<<S, THREADS, 0, stream>>>(x, W1, b1, W2, b2, W3t, b3, seg, out, N);
}

// Round 14
// 1805.250 us; speedup vs baseline: 1.4736x; 1.4736x over previous
//
#include <hip/hip_runtime.h>
#include <hip/hip_bf16.h>

// PhiNet: per-point MLP 16->128->128->64 (ReLU each) + segment mean (4096 segs x 256 pts).
// One block per segment, one lane per point. Weights via wave-uniform s_load (SGPR path),
// activations fully register-resident with static indexing (rule #20). W3 pre-transposed
// into d_ws so the fused L2/L3 loop reads contiguous scalar cachelines for both W2 and W3.
//
// R6 fix: launch_bounds(256,2) left LLVM's occupancy TARGET at default (4 waves/EU ->
// 128-VGPR budget) -> ~220-reg live set spilled to scratch (259 MB writes, VALUBusy 21%).
// amdgpu_waves_per_eu(2,2) pins the allocator window to 2 waves/EU = 256-VGPR budget.

#define THREADS 256

// ---- one-shot prep: W3 [64][128] -> W3t [128][64] ----
__global__ void transpose_w3(const float* __restrict__ W3, float* __restrict__ W3t) {
    int idx = blockIdx.x * blockDim.x + threadIdx.x;   // 0 .. 8191
    int k = idx >> 7;          // 0..63   (row of W3)
    int o = idx & 127;         // 0..127  (col of W3)
    if (idx < 64 * 128) W3t[o * 64 + k] = W3[k * 128 + o];
}

__global__ __attribute__((amdgpu_waves_per_eu(2, 2))) __launch_bounds__(THREADS)
void phinet_kernel(const float* __restrict__ x,
                   const float* __restrict__ W1, const float* __restrict__ b1,
                   const float* __restrict__ W2, const float* __restrict__ b2,
                   const float* __restrict__ W3t, const float* __restrict__ b3,
                   const int*   __restrict__ seg,
                   float* __restrict__ out, int N)
{
    const int s     = blockIdx.x;
    const int tid   = threadIdx.x;
    const int lane  = tid & 63;
    const int wave  = tid >> 6;
    const int start = seg[s];
    const int end   = seg[s + 1];

    __shared__ float partial[4][64];
    partial[wave][lane] = 0.0f;
    __syncthreads();

    for (int p = start + tid; p < end; p += THREADS) {
        // ---- load point features (coalesced: lane-consecutive p) ----
        float xv[16];
#pragma unroll
        for (int c = 0; c < 16; ++c)
            xv[c] = x[(size_t)c * (size_t)N + (size_t)p];

        // ---- layer 1: 16 -> 128, ReLU (W1 wave-uniform -> s_load) ----
        float h1[128];
#pragma unroll
        for (int j = 0; j < 128; ++j) {
            float a = b1[j];
#pragma unroll
            for (int c = 0; c < 16; ++c)
                a = fmaf(W1[j * 16 + c], xv[c], a);
            h1[j] = fmaxf(a, 0.0f);
        }

        // ---- layer 3 accumulators (init with bias) ----
        float h3[64];
#pragma unroll
        for (int k = 0; k < 64; ++k) h3[k] = b3[k];

        // ---- layer 2 (128x128) fused with layer 3 (64x128) ----
        // W2 row: 128 contiguous floats; W3t row: 64 contiguous floats -> s_load_dwordx16
        // runs. unroll 2: one-iteration scalar-load lookahead (~200cy L2 latency vs
        // ~384cy FMA issue per o) without the unroll-4 register bloat.
#pragma unroll 2
        for (int o = 0; o < 128; ++o) {
            float a0 = 0.0f, a1 = 0.0f, a2 = 0.0f, a3 = 0.0f;
#pragma unroll
            for (int i = 0; i < 128; i += 4) {
                a0 = fmaf(W2[o * 128 + i + 0], h1[i + 0], a0);
                a1 = fmaf(W2[o * 128 + i + 1], h1[i + 1], a1);
                a2 = fmaf(W2[o * 128 + i + 2], h1[i + 2], a2);
                a3 = fmaf(W2[o * 128 + i + 3], h1[i + 3], a3);
            }
            const float h2 = fmaxf(b2[o] + ((a0 + a1) + (a2 + a3)), 0.0f);
#pragma unroll
            for (int k = 0; k < 64; ++k)
                h3[k] = fmaf(W3t[o * 64 + k], h2, h3[k]);
        }

        // ---- per-wave butterfly reduce each of the 64 features ----
#pragma unroll
        for (int k = 0; k < 64; ++k) {
            float v = fmaxf(h3[k], 0.0f);
            v += __shfl_xor(v, 1);
            v += __shfl_xor(v, 2);
            v += __shfl_xor(v, 4);
            v += __shfl_xor(v, 8);
            v += __shfl_xor(v, 16);
            v += __shfl_xor(v, 32);
            if (lane == 0) partial[wave][k] += v;
        }
    }

    __syncthreads();

    // ---- final cross-wave reduce + mean, one thread per feature ----
    if (tid < 64) {
        const float cnt = (float)(end - start);
        float v = partial[0][tid] + partial[1][tid] + partial[2][tid] + partial[3][tid];
        out[(size_t)s * 64 + tid] = v / cnt;
    }
}

extern "C" void kernel_launch(void* const* d_in, const int* in_sizes, int n_in,
                              void* d_out, int out_size, void* d_ws, size_t ws_size,
                              hipStream_t stream) {
    const float* x  = (const float*)d_in[0];
    const float* W1 = (const float*)d_in[1];
    const float* b1 = (const float*)d_in[2];
    const float* W2 = (const float*)d_in[3];
    const float* b2 = (const float*)d_in[4];
    const float* W3 = (const float*)d_in[5];
    const float* b3 = (const float*)d_in[6];
    const int*  seg = (const int*)d_in[7];
    float* out = (float*)d_out;

    const int N = in_sizes[0] / 16;          // x is [1, 16, N]
    const int S = in_sizes[7] - 1;           // sample_indices has S+1 entries

    float* W3t = (float*)d_ws;               // 128*64*4 = 32 KB scratch

    transpose_w3<<<(64 * 128 + 255) / 256, 256, 0, stream>>>(W3, W3t);
    phinet_kernel<<<S, THREADS, 0, stream>>>(x, W1, b1, W2, b2, W3t, b3, seg, out, N);
}

// Round 15
// 928.471 us; speedup vs baseline: 2.8651x; 1.9443x over previous
//
#include <hip/hip_runtime.h>
#include <hip/hip_bf16.h>

// PhiNet: per-point MLP 16->128->128->64 (ReLU) + segment mean (4096 segs x 256 pts).
// R14 post-mortem: allocator pinned at 128 VGPR despite waves_per_eu(2,2); h1[128]+h3[64]
// live set spilled (~107 B/pt scratch). R15: restructure to FIT 128 regs honestly:
//   - never materialize h1: stream i, compute h1_i from xv on the fly
//   - accumulate h2 in 32-wide o-QUARTERS (acc[32]), fold each quarter into h3[64]
//   - L1 recomputed per quarter (+23% FLOPs) -- deterministic, vs nondeterministic spill
// Peak live ~ xv[16]+h3[64]+acc[32]+temps ~ 120 VGPR. W2 pre-transposed to W2t[i][o].

#define THREADS 256

// ---- one-shot prep: W2 [128][128] -> W2t[i][o]; W3 [64][128] -> W3t[o][k] ----
__global__ void transpose_w(const float* __restrict__ W2, const float* __restrict__ W3,
                            float* __restrict__ W2t, float* __restrict__ W3t) {
    int idx = blockIdx.x * blockDim.x + threadIdx.x;     // 0 .. 16383
    if (idx < 128 * 128) {
        int o = idx >> 7, i = idx & 127;
        W2t[i * 128 + o] = W2[o * 128 + i];
    }
    if (idx < 64 * 128) {
        int k = idx >> 7, o = idx & 127;
        W3t[o * 64 + k] = W3[k * 128 + o];
    }
}

__global__ __attribute__((amdgpu_waves_per_eu(3, 4))) __launch_bounds__(THREADS)
void phinet_kernel(const float* __restrict__ x,
                   const float* __restrict__ W1, const float* __restrict__ b1,
                   const float* __restrict__ W2t, const float* __restrict__ b2,
                   const float* __restrict__ W3t, const float* __restrict__ b3,
                   const int*   __restrict__ seg,
                   float* __restrict__ out, int N)
{
    const int s     = blockIdx.x;
    const int tid   = threadIdx.x;
    const int lane  = tid & 63;
    const int wave  = tid >> 6;
    const int start = seg[s];
    const int end   = seg[s + 1];

    __shared__ float partial[4][64];
    partial[wave][lane] = 0.0f;
    __syncthreads();

    for (int p = start + tid; p < end; p += THREADS) {
        // ---- point features (coalesced per channel: lane-consecutive p) ----
        float xv[16];
#pragma unroll
        for (int c = 0; c < 16; ++c)
            xv[c] = x[(size_t)c * (size_t)N + (size_t)p];

        // ---- h3 accumulators (init with bias; ReLU applied at reduce) ----
        float h3[64];
#pragma unroll
        for (int k = 0; k < 64; ++k) h3[k] = b3[k];

        // ---- o-quarters: L1+L2 fused over i, then fold through W3 ----
        for (int q = 0; q < 4; ++q) {                 // runtime loop (I$ size)
            const float* W2tq = W2t + q * 32;         // slice base (SGPR)
            const float* bq   = b2  + q * 32;
            float acc[32];
#pragma unroll
            for (int t = 0; t < 32; ++t) acc[t] = bq[t];

#pragma unroll 2
            for (int i = 0; i < 128; ++i) {
                // h1_i = relu(b1[i] + W1[i,:] . xv)   (W1 row: wave-uniform s_load)
                float a = b1[i];
#pragma unroll
                for (int c = 0; c < 16; ++c)
                    a = fmaf(W1[i * 16 + c], xv[c], a);
                const float h1i = fmaxf(a, 0.0f);
                // acc[t] += W2t[i][q*32+t] * h1_i   (32 contiguous floats: s_load)
#pragma unroll
                for (int t = 0; t < 32; ++t)
                    acc[t] = fmaf(W2tq[i * 128 + t], h1i, acc[t]);
            }

            // fold quarter into h3: h3[k] += W3t[o][k] * relu(acc)
#pragma unroll
            for (int t = 0; t < 32; ++t) {
                const float h2 = fmaxf(acc[t], 0.0f);
                const float* w3row = W3t + (q * 32 + t) * 64;   // 64 contiguous
#pragma unroll
                for (int k = 0; k < 64; ++k)
                    h3[k] = fmaf(w3row[k], h2, h3[k]);
            }
        }

        // ---- per-wave butterfly reduce each of the 64 features ----
#pragma unroll
        for (int k = 0; k < 64; ++k) {
            float v = fmaxf(h3[k], 0.0f);             // final ReLU, then mean
            v += __shfl_xor(v, 1);
            v += __shfl_xor(v, 2);
            v += __shfl_xor(v, 4);
            v += __shfl_xor(v, 8);
            v += __shfl_xor(v, 16);
            v += __shfl_xor(v, 32);
            if (lane == 0) partial[wave][k] += v;
        }
    }

    __syncthreads();

    // ---- final cross-wave reduce + mean, one thread per feature ----
    if (tid < 64) {
        const float cnt = (float)(end - start);
        float v = partial[0][tid] + partial[1][tid] + partial[2][tid] + partial[3][tid];
        out[(size_t)s * 64 + tid] = v / cnt;
    }
}

extern "C" void kernel_launch(void* const* d_in, const int* in_sizes, int n_in,
                              void* d_out, int out_size, void* d_ws, size_t ws_size,
                              hipStream_t stream) {
    const float* x  = (const float*)d_in[0];
    const float* W1 = (const float*)d_in[1];
    const float* b1 = (const float*)d_in[2];
    const float* W2 = (const float*)d_in[3];
    const float* b2 = (const float*)d_in[4];
    const float* W3 = (const float*)d_in[5];
    const float* b3 = (const float*)d_in[6];
    const int*  seg = (const int*)d_in[7];
    float* out = (float*)d_out;

    const int N = in_sizes[0] / 16;          // x is [1, 16, N]
    const int S = in_sizes[7] - 1;           // sample_indices has S+1 entries

    float* W2t = (float*)d_ws;               // 128*128*4 = 64 KB
    float* W3t = W2t + 128 * 128;            // 128*64*4  = 32 KB

    transpose_w<<<(128 * 128 + 255) / 256, 256, 0, stream>>>(W2, W3, W2t, W3t);
    phinet_kernel<<<S, THREADS, 0, stream>>>(x, W1, b1, W2t, b2, W3t, b3, seg, out, N);
}